// Round 4
// baseline (139.268 us; speedup 1.0000x reference)
//
#include <hip/hip_runtime.h>

// ---------------------------------------------------------------------------
// 3-dispatch gather splat, 8^3 tiles, one wave per tile, COLUMN RECORDS.
// History: R7 fat 64B per-(g,tile) records; R8 9x bin_prep split (~-4us);
// R9 splat LDS staging (-12us); R10 atomic padding + parallel atomics (NULL).
// R11 (this round): R0/R3 nulls kill contention+occupancy theories for
// bin_prep (~40us vs ~5us model). Survivors: device-atomic THROUGHPUT (500K
// return-value atomics) and scattered-16B-store THROUGHPUT (2M transactions).
// Both scale with pair count & record size -> restructure: ONE record per
// (gaussian, xy-column), 32B, stored at the center z-tile; z-extent <= +-6.2
// vox so splat tile tz scans center-slots tz-1..tz+1 concatenated and
// z-filters via a wave-uniform branch. x-table rebuilt in splat by a
// multiplicative ladder from precomputed q,r,s (no exp2 in the hot loop).
// Atomics 500K->253K, bin_prep stores 32MB/2M-txn -> 8MB/506K-txn, splat
// list read 32->8MB. ws use ~33 MB.
// ---------------------------------------------------------------------------

#define NTILE 32768           // 32^3 tiles of 8^3 voxels
#define CAP   32              // records per center-slot: avg ~7.7, Poisson-safe
#define LOG2E 1.4426950408889634f

typedef unsigned long long ull;

struct __align__(16) Rec {    // 32 B, one per (gaussian, x-y column)
    float cy, cz, w2;         // voxel-space center y,z; exp2 scale
    unsigned meta;            // [0:8) xmask, [8:16) mnz, [16:24) mxz_incl,
                              // [24:27) loy, [27:31) hiy
    float q, r, s;            // x-ladder: e0=q, e_{i+1}=e_i*r_i, r_{i+1}=r_i*s
    unsigned pad;
};

// ---- kernel 1: per-(Gaussian, tx, ty) column record --------------------------
__global__ __launch_bounds__(256) void bin_prep_kernel(
    const float* __restrict__ centers,
    const float* __restrict__ sigmas,
    const float* __restrict__ intens,
    int*  __restrict__ counts,
    Rec*  __restrict__ list,
    int N)
{
    int g = blockIdx.x * 256 + threadIdx.x;
    if (g >= N) return;
    int txi = blockIdx.y % 3;          // wave-uniform
    int tyi = blockIdx.y / 3;

    float cx = centers[3*g+0] * 255.0f;
    float cy = centers[3*g+1] * 255.0f;
    float cz = centers[3*g+2] * 255.0f;
    float sig = sigmas[g];
    float cut = 3.0f * sig * 255.0f;
    float cc[3] = {cx, cy, cz};
    int mn[3], mx[3];
    #pragma unroll
    for (int a = 0; a < 3; ++a) {
        mn[a] = (int)floorf(fmaxf(cc[a] - cut, 0.0f));
        mx[a] = (int)fminf(floorf(fminf(cc[a] + cut, 255.0f)) + 1.0f, 256.0f); // exclusive
    }
    float s255 = sig * 255.0f;
    float w2 = -0.5f * LOG2E / (s255 * s255);
    float inten = intens[g];

    int t0x = mn[0] >> 3, t1x = (mx[0] - 1) >> 3;
    int t0y = mn[1] >> 3, t1y = (mx[1] - 1) >> 3;

    int tx = t0x + txi; if (tx > t1x) return;
    int ty = t0y + tyi; if (ty > t1y) return;

    int ox = tx << 3, oy = ty << 3;
    int lox = max(mn[0] - ox, 0), hix = min(mx[0] - ox, 8);
    int loy = max(mn[1] - oy, 0), hiy = min(mx[1] - oy, 8);
    unsigned xm = (0xFFu << lox) & (0xFFu >> (8 - hix));   // hix in [1,8]

    float dx0 = (float)ox - cx;
    float q = exp2f(dx0 * dx0 * w2) * inten;
    float r = exp2f((2.0f * dx0 + 1.0f) * w2);
    float s = exp2f(2.0f * w2);

    int tzc = ((int)cz) >> 3;                  // cz in [0,255) -> tzc in [0,31]
    int t = (tx << 10) | (ty << 5) | tzc;
    unsigned meta = xm | ((unsigned)mn[2] << 8) | ((unsigned)(mx[2] - 1) << 16)
                  | ((unsigned)loy << 24) | ((unsigned)hiy << 27);

    int slot = atomicAdd(&counts[t], 1);
    if (slot < CAP) {
        int4* p = (int4*)&list[(size_t)t * CAP + slot];
        p[0] = make_int4(__float_as_int(cy), __float_as_int(cz),
                         __float_as_int(w2), (int)meta);
        p[1] = make_int4(__float_as_int(q), __float_as_int(r),
                         __float_as_int(s), 0);
    }
}

// ---- kernel 2: gather — one wave per tile, scans center-slots tz-1..tz+1 ---
__global__ __launch_bounds__(256) void splat_main(
    const int*  __restrict__ counts,
    const Rec*  __restrict__ list,
    float* __restrict__ vol)
{
    // concatenated staging: up to 3*CAP records (2 int4 each) + 1 pad record
    __shared__ int4 sh[4][(3 * CAP + 2) * 2];

    int wid = threadIdx.x >> 6;
    int lane = threadIdx.x & 63;
    int t = __builtin_amdgcn_readfirstlane(blockIdx.x * 4 + wid);
    int ox = (t >> 10) << 3, oy = ((t >> 5) & 31) << 3, oz = (t & 31) << 3;
    int tz = t & 31;
    int ly = lane >> 3, lz = lane & 7;

    int c0 = (tz > 0)  ? counts[t - 1] : 0;  if (c0 > CAP) c0 = CAP;
    int c1 = counts[t];                       if (c1 > CAP) c1 = CAP;
    int c2 = (tz < 31) ? counts[t + 1] : 0;  if (c2 > CAP) c2 = CAP;
    int n01 = c0 + c1, ntot = n01 + c2;

    const int4* s0 = (const int4*)(list + (long)(t - 1) * CAP);  // unused if c0==0
    const int4* s1 = (const int4*)(list + (long)t * CAP);
    const int4* s2 = (const int4*)(list + (long)(t + 1) * CAP);

    // stage concatenated lists, coalesced int4 chunks, wave-private (no barrier)
    for (int k = lane; k < 2 * ntot; k += 64) {
        const int4* src; int off;
        if (k < 2 * c0)       { src = s0; off = k; }
        else if (k < 2 * n01) { src = s1; off = k - 2 * c0; }
        else                  { src = s2; off = k - 2 * n01; }
        sh[wid][k] = src[off];
    }

    float fy = (float)(oy + ly);
    float fz = (float)(oz + lz);

    float acc[8];
    #pragma unroll
    for (int i = 0; i < 8; ++i) acc[i] = 0.0f;

    const int4* P = sh[wid];

    // depth-2 register pipeline over LDS broadcast reads
    int4 a0 = P[0], a1 = P[1];
    for (int k = 0; k < ntot; ++k) {
        int b = (k + 1) << 1;
        int4 b0 = P[b], b1 = P[b + 1];

        unsigned meta = (unsigned)__builtin_amdgcn_readfirstlane(a0.w);
        int mnz  = (int)((meta >> 8)  & 0xFF);
        int mxzi = (int)((meta >> 16) & 0xFF);
        int loz = mnz - oz;      if (loz < 0) loz = 0;
        int hiz = mxzi + 1 - oz; if (hiz > 8) hiz = 8;
        if (loz < hiz) {                       // z-overlap (wave-uniform branch)
            unsigned xm  = meta & 0xFF;
            int loy_ = (int)((meta >> 24) & 7);
            int hiy_ = (int)((meta >> 27) & 0xF);   // in [1,8]
            ull ym = ((~0ull) << (loy_ << 3)) & ((~0ull) >> (64 - (hiy_ << 3)));
            unsigned zpat = (0xFFu >> (8 - hiz)) & (0xFFu << loz);
            unsigned zrep = zpat * 0x01010101u;
            ull m = (((ull)zrep << 32) | (ull)zrep) & ym;

            float cyv = __int_as_float(a0.x), czv = __int_as_float(a0.y);
            float w2v = __int_as_float(a0.z);
            float qv = __int_as_float(a1.x), rv = __int_as_float(a1.y);
            float sv = __int_as_float(a1.z);

            float dy = fy - cyv, dz = fz - czv;
            float e = exp2f(fmaf(dy, dy, dz * dz) * w2v);
            float em;
            asm("v_cndmask_b32 %0, 0, %1, %2" : "=v"(em) : "v"(e), "s"(m));

            float ei = qv, ri = rv;
            #pragma unroll
            for (int i = 0; i < 8; ++i) {
                float v = (xm & (1u << i)) ? ei : 0.0f;  // uniform cond -> s_cselect
                acc[i] = fmaf(v, em, acc[i]);
                ei *= ri; ri *= sv;
            }
        }
        a0 = b0; a1 = b1;
    }

    int ybase = ((oy + ly) << 8) + (oz + lz);
    #pragma unroll
    for (int i = 0; i < 8; ++i)
        vol[((ox + i) << 16) + ybase] = acc[i];
}

// ---------------------------------------------------------------------------
extern "C" void kernel_launch(void* const* d_in, const int* in_sizes, int n_in,
                              void* d_out, int out_size, void* d_ws, size_t ws_size,
                              hipStream_t stream) {
    const float* centers = (const float*)d_in[0];   // (N,3)
    const float* sigmas  = (const float*)d_in[1];   // (N,)
    const float* intens  = (const float*)d_in[2];   // (N,)
    float* vol = (float*)d_out;                     // 256^3 fp32
    const int N = in_sizes[1];

    // workspace: counts 128KB | list NTILE*CAP*32B = 32 MiB
    char* ws = (char*)d_ws;
    int*  counts = (int*)ws;
    Rec*  list   = (Rec*)(ws + (size_t)NTILE * sizeof(int));

    hipMemsetAsync(counts, 0, (size_t)NTILE * sizeof(int), stream);

    int gblocks = (N + 255) / 256;
    bin_prep_kernel<<<dim3(gblocks, 9), 256, 0, stream>>>(centers, sigmas, intens,
                                                          counts, list, N);
    splat_main<<<NTILE / 4, 256, 0, stream>>>(counts, list, vol);
}

// Round 5
// 123.312 us; speedup vs baseline: 1.1294x; 1.1294x over previous
//
#include <hip/hip_runtime.h>

// ---------------------------------------------------------------------------
// 3-dispatch gather splat, 8^3 tiles, one wave per tile, COLUMN RECORDS.
// History: R7 fat 64B per-(g,tile) records; R8 9x bin_prep split; R9 splat
// LDS staging; R10 atomic padding (NULL -> contention theory dead);
// R11 column records + x-ladder: bin_prep 39->~30us but splat 37->61us,
// VALUBusy 63% => splat is VALU-inst-bound (~39 VALU/record from the ladder
// + per-tap cndmasks).
// R12 (this round): keep column records (253K atomics, small bin_prep
// traffic) but store the CLIPPED f32 x-table in the record (48B: cy,cz,w2,
// meta, ex[8]) exactly like the R7 fat record. Splat body = 15 VALU/record
// (dy,dz,dz2,fma,xw2,exp2,cndmask + 8 fma), y/z mask rebuild on the scalar
// pipe (co-issued). f32 ex (not f16) keeps arithmetic identical to the
// verified fat-record path => absmax unchanged. ws use ~50.5 MB.
// ---------------------------------------------------------------------------

#define NTILE 32768           // 32^3 tiles of 8^3 voxels
#define CAP   32              // records per center-slot: avg ~7.7, Poisson-safe
#define LOG2E 1.4426950408889634f

typedef unsigned long long ull;

struct __align__(16) Rec {    // 48 B, one per (gaussian, x-y column)
    float cy, cz, w2;         // voxel-space center y,z; exp2 scale
    unsigned meta;            // [0:8) mnz, [8:16) mxz_incl, [16:19) loy, [19:23) hiy
    float ex[8];              // clipped, intensity-folded x-table (zeros outside)
};

// ---- kernel 1: per-(Gaussian, tx, ty) column record ------------------------
__global__ __launch_bounds__(256) void bin_prep_kernel(
    const float* __restrict__ centers,
    const float* __restrict__ sigmas,
    const float* __restrict__ intens,
    int*  __restrict__ counts,
    Rec*  __restrict__ list,
    int N)
{
    int g = blockIdx.x * 256 + threadIdx.x;
    if (g >= N) return;
    int txi = blockIdx.y % 3;          // wave-uniform
    int tyi = blockIdx.y / 3;

    float cx = centers[3*g+0] * 255.0f;
    float cy = centers[3*g+1] * 255.0f;
    float cz = centers[3*g+2] * 255.0f;
    float sig = sigmas[g];
    float cut = 3.0f * sig * 255.0f;
    float cc[3] = {cx, cy, cz};
    int mn[3], mx[3];
    #pragma unroll
    for (int a = 0; a < 3; ++a) {
        mn[a] = (int)floorf(fmaxf(cc[a] - cut, 0.0f));
        mx[a] = (int)fminf(floorf(fminf(cc[a] + cut, 255.0f)) + 1.0f, 256.0f); // exclusive
    }
    float s255 = sig * 255.0f;
    float w2 = -0.5f * LOG2E / (s255 * s255);
    float inten = intens[g];

    int t0x = mn[0] >> 3, t1x = (mx[0] - 1) >> 3;
    int t0y = mn[1] >> 3, t1y = (mx[1] - 1) >> 3;

    int tx = t0x + txi; if (tx > t1x) return;
    int ty = t0y + tyi; if (ty > t1y) return;

    int ox = tx << 3, oy = ty << 3;
    int lox = max(mn[0] - ox, 0), hix = min(mx[0] - ox, 8);
    int loy = max(mn[1] - oy, 0), hiy = min(mx[1] - oy, 8);

    // clipped, intensity-folded x-table (identical math to verified fat path)
    float ex[8];
    #pragma unroll
    for (int i = 0; i < 8; ++i) {
        float d = (float)(ox + i) - cx;
        float v = exp2f(d * d * w2) * inten;
        ex[i] = (i >= lox && i < hix) ? v : 0.0f;
    }

    int tzc = ((int)cz) >> 3;                  // cz in [0,255) -> tzc in [0,31]
    int t = (tx << 10) | (ty << 5) | tzc;
    unsigned meta = (unsigned)mn[2] | ((unsigned)(mx[2] - 1) << 8)
                  | ((unsigned)loy << 16) | ((unsigned)hiy << 19);

    int slot = atomicAdd(&counts[t], 1);
    if (slot < CAP) {
        int4* p = (int4*)&list[(size_t)t * CAP + slot];
        p[0] = make_int4(__float_as_int(cy), __float_as_int(cz),
                         __float_as_int(w2), (int)meta);
        p[1] = make_int4(__float_as_int(ex[0]), __float_as_int(ex[1]),
                         __float_as_int(ex[2]), __float_as_int(ex[3]));
        p[2] = make_int4(__float_as_int(ex[4]), __float_as_int(ex[5]),
                         __float_as_int(ex[6]), __float_as_int(ex[7]));
    }
}

// ---- kernel 2: gather — one wave per tile, scans center-slots tz-1..tz+1 ---
__global__ __launch_bounds__(256) void splat_main(
    const int*  __restrict__ counts,
    const Rec*  __restrict__ list,
    float* __restrict__ vol)
{
    // concatenated staging: up to 3*CAP records (3 int4 each) + pad record
    __shared__ int4 sh[4][(3 * CAP + 2) * 3];   // 18.8 KB/block -> 32 waves/CU

    int wid = threadIdx.x >> 6;
    int lane = threadIdx.x & 63;
    int t = __builtin_amdgcn_readfirstlane(blockIdx.x * 4 + wid);
    int ox = (t >> 10) << 3, oy = ((t >> 5) & 31) << 3, oz = (t & 31) << 3;
    int tz = t & 31;
    int ly = lane >> 3, lz = lane & 7;

    int c0 = (tz > 0)  ? counts[t - 1] : 0;  if (c0 > CAP) c0 = CAP;
    int c1 = counts[t];                       if (c1 > CAP) c1 = CAP;
    int c2 = (tz < 31) ? counts[t + 1] : 0;  if (c2 > CAP) c2 = CAP;
    int n01 = c0 + c1, ntot = n01 + c2;

    const int4* s0 = (const int4*)(list + (long)(t - 1) * CAP);  // unused if c0==0
    const int4* s1 = (const int4*)(list + (long)t * CAP);
    const int4* s2 = (const int4*)(list + (long)(t + 1) * CAP);

    // stage concatenated lists, coalesced int4 chunks, wave-private (no barrier)
    int e0 = 3 * c0, e1 = 3 * n01, etot = 3 * ntot;
    for (int k = lane; k < etot; k += 64) {
        const int4* src; int off;
        if (k < e0)      { src = s0; off = k; }
        else if (k < e1) { src = s1; off = k - e0; }
        else             { src = s2; off = k - e1; }
        sh[wid][k] = src[off];
    }

    float fy = (float)(oy + ly);
    float fz = (float)(oz + lz);

    float acc[8];
    #pragma unroll
    for (int i = 0; i < 8; ++i) acc[i] = 0.0f;

    const int4* P = sh[wid];

    // depth-2 register pipeline over LDS broadcast reads
    int4 a0 = P[0], a1 = P[1], a2 = P[2];
    for (int k = 0; k < ntot; ++k) {
        int b = (k + 1) * 3;
        int4 b0 = P[b], b1 = P[b + 1], b2 = P[b + 2];

        unsigned meta = (unsigned)__builtin_amdgcn_readfirstlane(a0.w);
        int mnz  = (int)(meta & 0xFF);
        int mxzi = (int)((meta >> 8) & 0xFF);
        int loz = mnz - oz;      if (loz < 0) loz = 0;
        int hiz = mxzi + 1 - oz; if (hiz > 8) hiz = 8;
        if (loz < hiz) {                       // z-overlap (wave-uniform branch)
            int loy_ = (int)((meta >> 16) & 7);
            int hiy_ = (int)((meta >> 19) & 0xF);   // in [1,8]
            ull ym = ((~0ull) << (loy_ << 3)) & ((~0ull) >> (64 - (hiy_ << 3)));
            unsigned zpat = (0xFFu >> (8 - hiz)) & (0xFFu << loz);
            unsigned zrep = zpat * 0x01010101u;
            ull m = (((ull)zrep << 32) | (ull)zrep) & ym;

            float cyv = __int_as_float(a0.x), czv = __int_as_float(a0.y);
            float w2v = __int_as_float(a0.z);

            float dy = fy - cyv, dz = fz - czv;
            float e = exp2f(fmaf(dy, dy, dz * dz) * w2v);
            float em;
            asm("v_cndmask_b32 %0, 0, %1, %2" : "=v"(em) : "v"(e), "s"(m));

            acc[0] = fmaf(__int_as_float(a1.x), em, acc[0]);
            acc[1] = fmaf(__int_as_float(a1.y), em, acc[1]);
            acc[2] = fmaf(__int_as_float(a1.z), em, acc[2]);
            acc[3] = fmaf(__int_as_float(a1.w), em, acc[3]);
            acc[4] = fmaf(__int_as_float(a2.x), em, acc[4]);
            acc[5] = fmaf(__int_as_float(a2.y), em, acc[5]);
            acc[6] = fmaf(__int_as_float(a2.z), em, acc[6]);
            acc[7] = fmaf(__int_as_float(a2.w), em, acc[7]);
        }
        a0 = b0; a1 = b1; a2 = b2;
    }

    int ybase = ((oy + ly) << 8) + (oz + lz);
    #pragma unroll
    for (int i = 0; i < 8; ++i)
        vol[((ox + i) << 16) + ybase] = acc[i];
}

// ---------------------------------------------------------------------------
extern "C" void kernel_launch(void* const* d_in, const int* in_sizes, int n_in,
                              void* d_out, int out_size, void* d_ws, size_t ws_size,
                              hipStream_t stream) {
    const float* centers = (const float*)d_in[0];   // (N,3)
    const float* sigmas  = (const float*)d_in[1];   // (N,)
    const float* intens  = (const float*)d_in[2];   // (N,)
    float* vol = (float*)d_out;                     // 256^3 fp32
    const int N = in_sizes[1];

    // workspace: counts 128KB | list NTILE*CAP*48B ~= 50.3 MiB
    char* ws = (char*)d_ws;
    int*  counts = (int*)ws;
    Rec*  list   = (Rec*)(ws + (size_t)NTILE * sizeof(int));

    hipMemsetAsync(counts, 0, (size_t)NTILE * sizeof(int), stream);

    int gblocks = (N + 255) / 256;
    bin_prep_kernel<<<dim3(gblocks, 9), 256, 0, stream>>>(centers, sigmas, intens,
                                                          counts, list, N);
    splat_main<<<NTILE / 4, 256, 0, stream>>>(counts, list, vol);
}